// Round 2
// baseline (300.701 us; speedup 1.0000x reference)
//
#include <hip/hip_runtime.h>

// Beamform: 4 channels of interleaved complex f32; per 20-complex-sample unit
// a (1x4)@(4x5) complex combine with weight vector bf (8 floats, re/im
// interleaved). Output per unit: 10 floats [re0..re4, im0..im4].
//
// Round 4: single-variable A/B vs the round-0/2 kernel — NON-TEMPORAL stores.
// Evidence so far: two structurally different kernels (scalar/no-LDS vs
// float4/LDS-transpose) tie within 2% at ~115 us, 26% HBM peak, 8% VALUBusy.
// Neither shape nor occupancy nor WG count matters -> only remaining
// kernel-side lever is L3 residency: the 80 MB output stream allocates in
// L2/L3 each iteration and evicts ~80 MB of input (FETCH = 160 MB = half the
// input re-fetched per pass). nt stores (no-allocate) keep the output out of
// the caches, leaving more input L3-resident -> FETCH should drop toward
// ~80-130 MB. RFO already ruled out (round 1's full-sector contiguous stores
// left FETCH unchanged), so allocation policy is the only active mechanism.
//
// Work mapping (unchanged from round 0): 5 threads per unit, thread=(bl,c).
// Thread reads 4 float2 pairs x[10r+2c..+1] (r=0..3); wave's lanes cover a
// contiguous 2048-B window per load inst, L1 absorbs the 4x re-touch.
// Output unit b = ch*bpc + bl: out[b*10 + c] = re, out[b*10 + 5 + c] = im.

__global__ __launch_bounds__(256) void beamform_kernel(
    const float* __restrict__ in0, const float* __restrict__ in1,
    const float* __restrict__ in2, const float* __restrict__ in3,
    const float* __restrict__ bf, float* __restrict__ out,
    int blocksPerChannel, int threadsPerChannel)
{
    const int tid = blockIdx.x * blockDim.x + threadIdx.x;  // 0 .. 5*bpc-1
    if (tid >= threadsPerChannel) return;
    const int ch = blockIdx.y;  // channel 0..3

    const float* __restrict__ in =
        (ch == 0) ? in0 : (ch == 1) ? in1 : (ch == 2) ? in2 : in3;

    const int bl = tid / 5;         // unit within channel (magic-mul div)
    const int c  = tid - bl * 5;    // column 0..4

    // 4 aligned float2 loads: x[10r+2c], x[10r+2c+1]
    const float2* __restrict__ p =
        reinterpret_cast<const float2*>(in + (size_t)bl * 40 + 2 * c);
    // p is float2-indexed: element (10r+2c)/2 = 5r + c relative to bl*20
    const float2 x0 = p[0];
    const float2 x1 = p[5];
    const float2 x2 = p[10];
    const float2 x3 = p[15];

    // Uniform beamforming weights (scalar-cached).
    const float br0 = bf[0], bi0 = bf[1];
    const float br1 = bf[2], bi1 = bf[3];
    const float br2 = bf[4], bi2 = bf[5];
    const float br3 = bf[6], bi3 = bf[7];

    float re = br0 * x0.x - bi0 * x0.y;
    float im = bi0 * x0.x + br0 * x0.y;
    re += br1 * x1.x - bi1 * x1.y;
    im += bi1 * x1.x + br1 * x1.y;
    re += br2 * x2.x - bi2 * x2.y;
    im += bi2 * x2.x + br2 * x2.y;
    re += br3 * x3.x - bi3 * x3.y;
    im += bi3 * x3.x + br3 * x3.y;

    const size_t b = (size_t)ch * blocksPerChannel + bl;
    float* __restrict__ o = out + b * 10;
    // Non-temporal: do NOT allocate the output stream in L2/L3 — it is
    // never re-read by this kernel, and allocating it evicts input bytes
    // that must then be re-fetched from HBM on the next iteration.
    __builtin_nontemporal_store(re, o + c);
    __builtin_nontemporal_store(im, o + 5 + c);
}

extern "C" void kernel_launch(void* const* d_in, const int* in_sizes, int n_in,
                              void* d_out, int out_size, void* d_ws, size_t ws_size,
                              hipStream_t stream)
{
    const float* in0 = (const float*)d_in[0];
    const float* in1 = (const float*)d_in[1];
    const float* in2 = (const float*)d_in[2];
    const float* in3 = (const float*)d_in[3];
    const float* bf  = (const float*)d_in[4];
    float* out = (float*)d_out;

    const int len = in_sizes[0];               // 20,000,000 interleaved floats
    const int blocksPerChannel = len / 40;     // 500,000 units / channel
    const int threadsPerChannel = blocksPerChannel * 5;

    const int block = 256;
    dim3 grid((threadsPerChannel + block - 1) / block, 4, 1);
    beamform_kernel<<<grid, dim3(block, 1, 1), 0, stream>>>(
        in0, in1, in2, in3, bf, out, blocksPerChannel, threadsPerChannel);
}